// Round 6
// baseline (252.054 us; speedup 1.0000x reference)
//
#include <hip/hip_runtime.h>
#include <stdint.h>

// MHA fused: qkv = x @ w_qkv ; attention ; out [b,s,E] fp32
// Round 6: attn = barrier-free inner loop (K/V per-lane from L1/L2, no LDS
// staging; XCD swizzle makes K/V L2-resident). GEMM = 128x256 tile, 8 waves,
// bn-chunked XCD swizzle, m97 2-barrier loop, two-half coalesced epilogue.

typedef __attribute__((ext_vector_type(8))) short v8s;   // 8 x bf16 (4 VGPR)
typedef __attribute__((ext_vector_type(4))) float v4f;   // MFMA accum

__device__ __forceinline__ unsigned short bf16bits(float f) {
  union { float f; unsigned int u; } c; c.f = f;
  unsigned int u = c.u;
  unsigned int r = (u + 0x7fffu + ((u >> 16) & 1u)) >> 16;  // RNE
  return (unsigned short)r;
}

__device__ __forceinline__ v4f mfma16(v8s a, v8s b, v4f c) {
  return __builtin_amdgcn_mfma_f32_16x16x32_bf16(a, b, c, 0, 0, 0);
}

// async global->LDS, 16B per lane; lds dest must be wave-uniform base.
#define GLD16(g, l) __builtin_amdgcn_global_load_lds( \
    (const __attribute__((address_space(1))) unsigned int*)(g), \
    (__attribute__((address_space(3))) unsigned int*)(l), 16, 0, 0)

// ---------------- prep: x fp32 -> bf16 ----------------
__global__ __launch_bounds__(256) void cvt_x_kernel(const float4* __restrict__ x4,
                                                    ushort4* __restrict__ o4, int n4) {
  int i = blockIdx.x * 256 + threadIdx.x;
  if (i < n4) {
    float4 v = x4[i];
    ushort4 o;
    o.x = bf16bits(v.x); o.y = bf16bits(v.y); o.z = bf16bits(v.z); o.w = bf16bits(v.w);
    o4[i] = o;
  }
}

// ---------------- prep: w [1024][3072] f32 -> wT [3072][1024] bf16 ----------------
__global__ __launch_bounds__(256) void cvt_wT_kernel(const float* __restrict__ w,
                                                     unsigned short* __restrict__ wt) {
  __shared__ float t[32][33];
  int n0 = blockIdx.x * 32, k0 = blockIdx.y * 32;
  int tx = threadIdx.x & 31, ty = threadIdx.x >> 5;  // 32 x 8
  for (int i = 0; i < 4; ++i) {
    int kr = ty + i * 8;
    t[kr][tx] = w[(k0 + kr) * 3072 + n0 + tx];
  }
  __syncthreads();
  for (int i = 0; i < 4; ++i) {
    int nr = ty + i * 8;
    wt[(n0 + nr) * 1024 + k0 + tx] = bf16bits(t[tx][nr]);
  }
}

// ---------------- QKV GEMM: 128x256 tile, BK=64, 512 thr (8 waves 2x4) ----------------
// A = x_bf [4096][1024], B = wT [3072][1024]. Each wave 64x64, acc 4x4.
// XCD swizzle: bn-chunked so each XCD's <=3 B-panels stay L2-resident.
// bn<8 -> Cq[4096][2048] (Q|K); bn>=8 -> transposed restage to VT[bh][64][2048].
__global__ __launch_bounds__(512, 2) void qkv_gemm(const unsigned short* __restrict__ A,
                                                   const unsigned short* __restrict__ Bm,
                                                   unsigned short* __restrict__ Cq,
                                                   unsigned short* __restrict__ VTh) {
  __shared__ __align__(16) unsigned short S[24576];   // 48KB: As 8192 + Bs 16384
  unsigned short* As = S;          // [128][64]
  unsigned short* Bs = S + 8192;   // [256][64]
  int tid = threadIdx.x, lane = tid & 63, wave = tid >> 6;
  int wr = wave >> 2, wc = wave & 3;
  int flat = blockIdx.x + (blockIdx.y << 5);          // grid (32,12) -> 0..383
  int swz = (flat & 7) * 48 + (flat >> 3);            // bijective, 384 % 8 == 0
  int bm = swz & 31, bn = swz >> 5;

  v4f acc[4][4];
  for (int i = 0; i < 4; ++i)
    for (int j = 0; j < 4; ++j) acc[i][j] = (v4f){0.f, 0.f, 0.f, 0.f};

  for (int kt = 0; kt < 16; ++kt) {
    __syncthreads();                                  // prev reads done
    int kk = kt * 64;
    for (int i = 0; i < 2; ++i) {                     // A: 1024 chunks
      int e = i * 512 + tid;
      int row = e >> 3, cc = e & 7;
      int sc = cc ^ (row & 7);
      GLD16(A + (bm * 128 + row) * 1024 + kk + sc * 8,
            (char*)As + (i * 512 + wave * 64) * 16);
    }
    for (int i = 0; i < 4; ++i) {                     // B: 2048 chunks
      int e = i * 512 + tid;
      int row = e >> 3, cc = e & 7;
      int sc = cc ^ (row & 7);
      GLD16(Bm + (bn * 256 + row) * 1024 + kk + sc * 8,
            (char*)Bs + (i * 512 + wave * 64) * 16);
    }
    __syncthreads();                                  // tile landed
    for (int ks = 0; ks < 2; ++ks) {
      v8s af[4], bf[4];
      for (int rt = 0; rt < 4; ++rt) {
        int ra = wr * 64 + rt * 16 + (lane & 15);
        int ca = (ks * 4 + (lane >> 4)) ^ (ra & 7);
        af[rt] = *(const v8s*)&As[ra * 64 + ca * 8];
      }
      for (int ct = 0; ct < 4; ++ct) {
        int rb = wc * 64 + ct * 16 + (lane & 15);
        int cb = (ks * 4 + (lane >> 4)) ^ (rb & 7);
        bf[ct] = *(const v8s*)&Bs[rb * 64 + cb * 8];
      }
      for (int rt = 0; rt < 4; ++rt)
        for (int ct = 0; ct < 4; ++ct)
          acc[rt][ct] = mfma16(af[rt], bf[ct], acc[rt][ct]);
    }
  }
  __syncthreads();                                    // free S for restage

  if (bn < 8) {
    // Q|K: two 128x128 halves (by wc pair), swizzled restage + 16B stores
    for (int h = 0; h < 2; ++h) {
      if ((wc >> 1) == h) {
        for (int ct = 0; ct < 4; ++ct) {
          int col = (wc & 1) * 64 + ct * 16 + (lane & 15);   // 0..127
          for (int rt = 0; rt < 4; ++rt)
            for (int j = 0; j < 4; ++j) {
              int m = wr * 64 + rt * 16 + ((lane >> 4) << 2) + j;
              S[m * 128 + (((col >> 3) ^ (m & 7)) << 3) + (col & 7)] =
                  bf16bits(acc[rt][ct][j]);
            }
        }
      }
      __syncthreads();
      for (int i = 0; i < 4; ++i) {
        int c = i * 512 + tid;                        // 2048 chunks: 128m x 16
        int m = c >> 4, c8 = c & 15;
        v8s v = *(const v8s*)&S[m * 128 + ((c8 ^ (m & 7)) << 3)];
        *(v8s*)&Cq[(size_t)(bm * 128 + m) * 2048 + bn * 256 + h * 128 + c8 * 8] = v;
      }
      __syncthreads();
    }
  } else {
    // V: two transposed halves ST[256 n][64 m] (by wr), to VT[bh][64][2048]
    int b = bm >> 4, s0 = (bm & 15) * 128;
    for (int h = 0; h < 2; ++h) {
      if (wr == h) {
        for (int ct = 0; ct < 4; ++ct) {
          int n = wc * 64 + ct * 16 + (lane & 15);    // 0..255
          for (int rt = 0; rt < 4; ++rt) {
            int m0 = rt * 16 + ((lane >> 4) << 2);    // 0..63 within half
            ushort4 p4;
            p4.x = bf16bits(acc[rt][ct][0]); p4.y = bf16bits(acc[rt][ct][1]);
            p4.z = bf16bits(acc[rt][ct][2]); p4.w = bf16bits(acc[rt][ct][3]);
            *(ushort4*)&S[n * 64 + (((m0 >> 3) ^ (n & 7)) << 3) + (m0 & 7)] = p4;
          }
        }
      }
      __syncthreads();
      for (int i = 0; i < 4; ++i) {
        int c = i * 512 + tid;                        // 2048 chunks: 256n x 8
        int n = c >> 3, c8 = c & 7;
        v8s v = *(const v8s*)&S[n * 64 + ((c8 ^ (n & 7)) << 3)];
        int nn = bn * 256 + n - 2048;                 // v-col 0..1023
        int head = nn >> 6, d = nn & 63;
        *(v8s*)&VTh[(size_t)((b * 16 + head) * 64 + d) * 2048 + s0 + h * 64 + c8 * 8] = v;
      }
      __syncthreads();
    }
  }
}

// ---------------- attention: barrier-free inner loop ----------------
// Block = 4 waves x 32 q-rows (QBLK=128). K/V fragments loaded per-lane from
// global (L1/L2; XCD swizzle keeps the XCD's 4 bh K/V in its L2). Only Q and
// wave-private P in LDS -> NO __syncthreads in the k-loop.
__global__ __launch_bounds__(256, 2) void attn_kernel(const unsigned short* __restrict__ Cq,
                                                      const unsigned short* __restrict__ VTh,
                                                      float* __restrict__ out) {
  __shared__ __align__(16) unsigned short Qs[128 * 64];  // 16KB
  __shared__ __align__(16) unsigned short Ps[128 * 64];  // 16KB, wave-private rows
  int tid = threadIdx.x, lane = tid & 63, wave = tid >> 6;
  int wq = wave * 32;
  int flat = blockIdx.x + (blockIdx.y << 4);             // grid (16,32) -> 0..511
  int swz = (flat & 7) * 64 + (flat >> 3);               // bijective, 512 % 8 == 0
  int qb = swz & 15, bh = swz >> 4;                      // XCD x owns bh in [4x,4x+4)
  int b = bh >> 4, h = bh & 15;

  const unsigned short* Qg = Cq + (size_t)(b * 2048 + qb * 128) * 2048 + h * 64;
  const unsigned short* Kg = Cq + (size_t)(b * 2048) * 2048 + 1024 + h * 64;
  const unsigned short* Vg = VTh + (size_t)bh * 64 * 2048;

  for (int i = 0; i < 4; ++i) {                  // Q tile 128x64, swizzled fill
    int e = i * 256 + tid;
    int row = e >> 3, cc = e & 7;
    int sc = cc ^ (row & 7);
    GLD16(Qg + (size_t)row * 2048 + sc * 8, (char*)Qs + (i * 256 + wave * 64) * 16);
  }
  __syncthreads();                               // the only block barrier

  v8s qf[2][2];
  for (int rt = 0; rt < 2; ++rt)
    for (int ks = 0; ks < 2; ++ks) {
      int rq = wq + rt * 16 + (lane & 15);
      int cq = (ks * 4 + (lane >> 4)) ^ (rq & 7);
      qf[rt][ks] = *(const v8s*)&Qs[rq * 64 + cq * 8];
    }

  v4f oacc[2][4];
  for (int i = 0; i < 2; ++i)
    for (int j = 0; j < 4; ++j) oacc[i][j] = (v4f){0.f, 0.f, 0.f, 0.f};
  float rsum[2][4] = {};

  for (int kt = 0; kt < 32; ++kt) {
    // scores: S = Q.K^T, K frags straight from global (L1/L2)
    v4f sacc[2][4];
    for (int i = 0; i < 2; ++i)
      for (int j = 0; j < 4; ++j) sacc[i][j] = (v4f){0.f, 0.f, 0.f, 0.f};
    for (int ks = 0; ks < 2; ++ks) {
      v8s kf[4];
      for (int ct = 0; ct < 4; ++ct)
        kf[ct] = *(const v8s*)&Kg[(size_t)(kt * 64 + ct * 16 + (lane & 15)) * 2048 +
                                  ks * 32 + (lane >> 4) * 8];
      for (int rt = 0; rt < 2; ++rt)
        for (int ct = 0; ct < 4; ++ct)
          sacc[rt][ct] = mfma16(qf[rt][ks], kf[ct], sacc[rt][ct]);
    }

    // P = exp(scale*S); rsum; stage P (trunc-pack) into wave-private LDS rows
    for (int rt = 0; rt < 2; ++rt)
      for (int ct = 0; ct < 4; ++ct)
        for (int j = 0; j < 4; ++j) {
          float p = __expf(sacc[rt][ct][j] * 0.03125f);
          rsum[rt][j] += p;
          union { float f; unsigned int u; } cv; cv.f = p;
          int prow = wq + rt * 16 + ((lane >> 4) << 2) + j;
          int col = ct * 16 + (lane & 15);
          Ps[prow * 64 + (((col >> 3) ^ (prow & 7)) << 3) + (col & 7)] =
              (unsigned short)(cv.u >> 16);
        }

    // O += P.V, V frags straight from global (VT layout)
    for (int ks4 = 0; ks4 < 2; ++ks4) {
      v8s pa[2], vb[4];
      for (int rt = 0; rt < 2; ++rt) {
        int rp = wq + rt * 16 + (lane & 15);
        int cp = (ks4 * 4 + (lane >> 4)) ^ (rp & 7);
        pa[rt] = *(const v8s*)&Ps[rp * 64 + cp * 8];
      }
      for (int dt = 0; dt < 4; ++dt)
        vb[dt] = *(const v8s*)&Vg[(size_t)(dt * 16 + (lane & 15)) * 2048 +
                                  kt * 64 + ks4 * 32 + (lane >> 4) * 8];
      for (int rt = 0; rt < 2; ++rt)
        for (int dt = 0; dt < 4; ++dt)
          oacc[rt][dt] = mfma16(pa[rt], vb[dt], oacc[rt][dt]);
    }
  }

  // complete row sums across the 16-lane col groups
  for (int rt = 0; rt < 2; ++rt)
    for (int j = 0; j < 4; ++j) {
      float v = rsum[rt][j];
      v += __shfl_xor(v, 1, 64);
      v += __shfl_xor(v, 2, 64);
      v += __shfl_xor(v, 4, 64);
      v += __shfl_xor(v, 8, 64);
      rsum[rt][j] = v;
    }

  for (int rt = 0; rt < 2; ++rt)
    for (int dt = 0; dt < 4; ++dt) {
      int q = qb * 128 + wq + rt * 16 + ((lane >> 4) << 2);
      int d = h * 64 + dt * 16 + (lane & 15);
      for (int j = 0; j < 4; ++j)
        out[(size_t)(b * 2048 + q + j) * 1024 + d] = oacc[rt][dt][j] / rsum[rt][j];
    }
}

extern "C" void kernel_launch(void* const* d_in, const int* in_sizes, int n_in,
                              void* d_out, int out_size, void* d_ws, size_t ws_size,
                              hipStream_t stream) {
  const float* x = (const float*)d_in[0];   // [2,2048,1024]
  const float* w = (const float*)d_in[1];   // [1024,3072]
  float* out = (float*)d_out;

  char* ws = (char*)d_ws;
  unsigned short* xb = (unsigned short*)ws;                  // [4096][1024] bf16, 8 MB
  unsigned short* wT = (unsigned short*)(ws + 8388608);      // [3072][1024] bf16, 6 MB
  unsigned short* Cq = (unsigned short*)(ws + 14680064);     // [4096][2048] bf16, 16 MB (Q|K)
  unsigned short* VT = (unsigned short*)(ws + 31457280);     // [32][64][2048] bf16, 8 MB

  cvt_x_kernel<<<4096, 256, 0, stream>>>((const float4*)x, (ushort4*)xb, 1048576);
  cvt_wT_kernel<<<dim3(96, 32), 256, 0, stream>>>(w, wT);
  qkv_gemm<<<dim3(32, 12), 512, 0, stream>>>(xb, wT, Cq, VT);
  attn_kernel<<<dim3(16, 32), 256, 0, stream>>>(Cq, VT, out);
}

// Round 11
// 156.218 us; speedup vs baseline: 1.6135x; 1.6135x over previous
//
#include <hip/hip_runtime.h>
#include <stdint.h>

// MHA fused: qkv = x @ w_qkv ; attention ; out [b,s,E] fp32
// Round 11 = round-7 design with one fix: __exp2f (not a device intrinsic,
// compile error) -> __builtin_amdgcn_exp2f (lowers to v_exp_f32 = native 2^x).
// attn: 32x32x16 MFMA, swapped QK^T (mfma(K,Q)), in-register softmax via
// v_cvt_pk_bf16_f32 + v_permlane32_swap_b32. GEMM: round-5 structure +
// Q pre-scaled by log2(e)/32.

typedef __attribute__((ext_vector_type(8))) short v8s;     // 8 x bf16
typedef __attribute__((ext_vector_type(4))) float v4f;     // 16x16 accum
typedef __attribute__((ext_vector_type(16))) float f32x16; // 32x32 accum

__device__ __forceinline__ unsigned short bf16bits(float f) {
  union { float f; unsigned int u; } c; c.f = f;
  unsigned int u = c.u;
  unsigned int r = (u + 0x7fffu + ((u >> 16) & 1u)) >> 16;  // RNE
  return (unsigned short)r;
}

__device__ __forceinline__ v4f mfma16(v8s a, v8s b, v4f c) {
  return __builtin_amdgcn_mfma_f32_16x16x32_bf16(a, b, c, 0, 0, 0);
}
__device__ __forceinline__ f32x16 mfma32(v8s a, v8s b, f32x16 c) {
  return __builtin_amdgcn_mfma_f32_32x32x16_bf16(a, b, c, 0, 0, 0);
}
__device__ __forceinline__ f32x16 zero16() {
  f32x16 z;
#pragma unroll
  for (int i = 0; i < 16; ++i) z[i] = 0.f;
  return z;
}
__device__ __forceinline__ unsigned int cvtpk(float lo, float hi) {
  unsigned int r;
  asm("v_cvt_pk_bf16_f32 %0, %1, %2" : "=v"(r) : "v"(lo), "v"(hi));
  return r;
}
__device__ __forceinline__ void pl32swap(unsigned int& a, unsigned int& b) {
  asm volatile("v_permlane32_swap_b32 %0, %1" : "+v"(a), "+v"(b));
}

// async global->LDS, 16B per lane; lds dest must be wave-uniform base.
#define GLD16(g, l) __builtin_amdgcn_global_load_lds( \
    (const __attribute__((address_space(1))) unsigned int*)(g), \
    (__attribute__((address_space(3))) unsigned int*)(l), 16, 0, 0)

// ---------------- prep: x fp32 -> bf16 ----------------
__global__ __launch_bounds__(256) void cvt_x_kernel(const float4* __restrict__ x4,
                                                    ushort4* __restrict__ o4, int n4) {
  int i = blockIdx.x * 256 + threadIdx.x;
  if (i < n4) {
    float4 v = x4[i];
    ushort4 o;
    o.x = bf16bits(v.x); o.y = bf16bits(v.y); o.z = bf16bits(v.z); o.w = bf16bits(v.w);
    o4[i] = o;
  }
}

// ---------------- prep: w [1024][3072] f32 -> wT [3072][1024] bf16 ----------------
__global__ __launch_bounds__(256) void cvt_wT_kernel(const float* __restrict__ w,
                                                     unsigned short* __restrict__ wt) {
  __shared__ float t[32][33];
  int n0 = blockIdx.x * 32, k0 = blockIdx.y * 32;
  int tx = threadIdx.x & 31, ty = threadIdx.x >> 5;  // 32 x 8
  for (int i = 0; i < 4; ++i) {
    int kr = ty + i * 8;
    t[kr][tx] = w[(k0 + kr) * 3072 + n0 + tx];
  }
  __syncthreads();
  for (int i = 0; i < 4; ++i) {
    int nr = ty + i * 8;
    wt[(n0 + nr) * 1024 + k0 + tx] = bf16bits(t[tx][nr]);
  }
}

// ---------------- QKV GEMM (round-5 structure) ----------------
// Tile 64x128, BK=64, 4 waves 2x2 (wave 32x64), dbuf LDS, 1 barrier/iter.
// Q cols (bn<8) pre-scaled by log2(e)/32 so attn uses exp2 directly.
__global__ __launch_bounds__(256) void qkv_gemm(const unsigned short* __restrict__ A,
                                                const unsigned short* __restrict__ Bm,
                                                unsigned short* __restrict__ Cq,
                                                unsigned short* __restrict__ VTh) {
  __shared__ __align__(16) unsigned short S[24576];   // 48 KB
  int bm = blockIdx.x, bn = blockIdx.y;
  int tid = threadIdx.x, lane = tid & 63, wave = tid >> 6;
  int wr = wave >> 1, wc = wave & 1;

  v4f acc[2][4];
  for (int i = 0; i < 2; ++i)
    for (int j = 0; j < 4; ++j) acc[i][j] = (v4f){0.f, 0.f, 0.f, 0.f};

  auto STAGE = [&](int hh, int kk) {
    unsigned short* As = S + hh * 12288;
    unsigned short* Bs = As + 4096;
    for (int i = 0; i < 2; ++i) {
      int e = i * 256 + tid;
      int row = e >> 3, cc = e & 7;
      int sc = cc ^ (row & 7);
      GLD16(A + (bm * 64 + row) * 1024 + kk + sc * 8,
            (char*)As + (i * 256 + wave * 64) * 16);
    }
    for (int i = 0; i < 4; ++i) {
      int e = i * 256 + tid;
      int row = e >> 3, cc = e & 7;
      int sc = cc ^ (row & 7);
      GLD16(Bm + (bn * 128 + row) * 1024 + kk + sc * 8,
            (char*)Bs + (i * 256 + wave * 64) * 16);
    }
  };
  auto COMPUTE = [&](int hh) {
    const unsigned short* As = S + hh * 12288;
    const unsigned short* Bs = As + 4096;
    for (int ks = 0; ks < 2; ++ks) {
      v8s af[2], bf[4];
      for (int rt = 0; rt < 2; ++rt) {
        int ra = wr * 32 + rt * 16 + (lane & 15);
        int ca = (ks * 4 + (lane >> 4)) ^ (ra & 7);
        af[rt] = *(const v8s*)&As[ra * 64 + ca * 8];
      }
      for (int ct = 0; ct < 4; ++ct) {
        int rb = wc * 64 + ct * 16 + (lane & 15);
        int cb = (ks * 4 + (lane >> 4)) ^ (rb & 7);
        bf[ct] = *(const v8s*)&Bs[rb * 64 + cb * 8];
      }
      for (int rt = 0; rt < 2; ++rt)
        for (int ct = 0; ct < 4; ++ct)
          acc[rt][ct] = mfma16(af[rt], bf[ct], acc[rt][ct]);
    }
  };

  STAGE(0, 0);
  __syncthreads();
  for (int kt = 0; kt < 15; ++kt) {
    STAGE((kt + 1) & 1, (kt + 1) * 64);
    COMPUTE(kt & 1);
    __syncthreads();
  }
  COMPUTE(1);
  __syncthreads();

  if (bn < 16) {
    float qs = (bn < 8) ? 0.0450842200f : 1.0f;     // log2(e)/32 folded into Q
    for (int ct = 0; ct < 4; ++ct) {
      int col = wc * 64 + ct * 16 + (lane & 15);
      for (int rt = 0; rt < 2; ++rt)
        for (int j = 0; j < 4; ++j) {
          int m = wr * 32 + rt * 16 + ((lane >> 4) << 2) + j;
          S[m * 128 + (((col >> 3) ^ (m & 7)) << 3) + (col & 7)] =
              bf16bits(acc[rt][ct][j] * qs);
        }
    }
    __syncthreads();
    for (int i = 0; i < 4; ++i) {
      int c = i * 256 + tid;
      int m = c >> 4, c8 = c & 15;
      v8s v = *(const v8s*)&S[m * 128 + ((c8 ^ (m & 7)) << 3)];
      *(v8s*)&Cq[(size_t)(bm * 64 + m) * 2048 + bn * 128 + c8 * 8] = v;
    }
  } else {
    for (int ct = 0; ct < 4; ++ct) {
      int n = wc * 64 + ct * 16 + (lane & 15);
      for (int rt = 0; rt < 2; ++rt) {
        int m0 = wr * 32 + rt * 16 + ((lane >> 4) << 2);
        ushort4 p4;
        p4.x = bf16bits(acc[rt][ct][0]); p4.y = bf16bits(acc[rt][ct][1]);
        p4.z = bf16bits(acc[rt][ct][2]); p4.w = bf16bits(acc[rt][ct][3]);
        *(ushort4*)&S[n * 64 + (((m0 >> 3) ^ (n & 7)) << 3) + (m0 & 7)] = p4;
      }
    }
    __syncthreads();
    int b = bm >> 5, s0 = (bm & 31) * 64;
    for (int i = 0; i < 4; ++i) {
      int c = i * 256 + tid;
      int n = c >> 3, c8 = c & 7;
      v8s v = *(const v8s*)&S[n * 64 + ((c8 ^ (n & 7)) << 3)];
      int nn = bn * 128 + n - 2048;
      int head = nn >> 6, d = nn & 63;
      *(v8s*)&VTh[(size_t)((b * 16 + head) * 64 + d) * 2048 + s0 + c8 * 8] = v;
    }
  }
}

// ---------------- attention: 32x32 swapped-MFMA, in-register softmax ----------------
// 4 waves x 32 q-rows (QBLK=128). Per k-tile (64 keys):
//  S^T = mfma32(K, Q): lane owns q=lane&31, keys (r&3)+8*(r>>2)+4h (+32*mt)
//  P = exp2(S) in-register; pack cvt_pk; permlane32_swap -> PV A-frags; PV mfma32.
__global__ __launch_bounds__(256) void attn_kernel(const unsigned short* __restrict__ Cq,
                                                   const unsigned short* __restrict__ VTh,
                                                   float* __restrict__ out) {
  __shared__ __align__(16) unsigned short Qs[128 * 64];  // [q][d] 16KB
  __shared__ __align__(16) unsigned short Ks[64 * 64];   // [key][d] 8KB
  __shared__ __align__(16) unsigned short Vs[64 * 64];   // [d][key] 8KB
  int tid = threadIdx.x, lane = tid & 63, wave = tid >> 6;
  int ln31 = lane & 31, h = lane >> 5;
  int wq = wave * 32;
  int flat = blockIdx.x + (blockIdx.y << 4);             // grid (16,32)
  int swz = (flat & 7) * 64 + (flat >> 3);               // XCD x owns bh 4x..4x+3
  int qb = swz & 15, bh = swz >> 4;
  int b = bh >> 4, hH = bh & 15;

  const unsigned short* Qg = Cq + (size_t)(b * 2048 + qb * 128) * 2048 + hH * 64;
  const unsigned short* Kg = Cq + (size_t)(b * 2048) * 2048 + 1024 + hH * 64;
  const unsigned short* Vg = VTh + (size_t)bh * 64 * 2048;

  for (int i = 0; i < 4; ++i) {                  // Q tile 128x64 (swizzled fill)
    int e = i * 256 + tid;
    int row = e >> 3, cc = e & 7;
    int sc = cc ^ (row & 7);
    GLD16(Qg + (size_t)row * 2048 + sc * 8, (char*)Qs + (i * 256 + wave * 64) * 16);
  }
  __syncthreads();

  v8s qf[4];                                     // Q row q=wq+ln31, d-chunks
#pragma unroll
  for (int ks = 0; ks < 4; ++ks) {
    int rq = wq + ln31;
    int cq = (ks * 2 + h) ^ (rq & 7);
    qf[ks] = *(const v8s*)&Qs[rq * 64 + cq * 8];
  }

  f32x16 acc0 = zero16(), acc1 = zero16();
  float rsum = 0.f;

  for (int kt = 0; kt < 32; ++kt) {
    __syncthreads();                             // prior tile reads done
    for (int i = 0; i < 2; ++i) {                // K tile 64x64
      int e = i * 256 + tid;
      int row = e >> 3, cc = e & 7;
      int sc = cc ^ (row & 7);
      GLD16(Kg + (size_t)(kt * 64 + row) * 2048 + sc * 8,
            (char*)Ks + (i * 256 + wave * 64) * 16);
    }
    for (int i = 0; i < 2; ++i) {                // VT tile [d][64-key slice]
      int e = i * 256 + tid;
      int row = e >> 3, cc = e & 7;
      int sc = cc ^ (row & 7);
      GLD16(Vg + row * 2048 + kt * 64 + sc * 8, (char*)Vs + (i * 256 + wave * 64) * 16);
    }
    __syncthreads();

    // S^T = mfma32(K, Q): s0 = keys 0..31, s1 = keys 32..63 (rows), col q
    f32x16 s0 = zero16(), s1 = zero16();
#pragma unroll
    for (int ks = 0; ks < 4; ++ks) {
      int ck = (ks * 2 + h) ^ (ln31 & 7);        // same for row and row+32
      v8s kf0 = *(const v8s*)&Ks[ln31 * 64 + ck * 8];
      v8s kf1 = *(const v8s*)&Ks[(32 + ln31) * 64 + ck * 8];
      s0 = mfma32(kf0, qf[ks], s0);
      s1 = mfma32(kf1, qf[ks], s1);
    }

    // per 32-key block: exp2, pack, permlane-redistribute, PV
#pragma unroll
    for (int mt = 0; mt < 2; ++mt) {
      const f32x16 st = mt ? s1 : s0;
      float p[16];
#pragma unroll
      for (int r = 0; r < 16; ++r) { p[r] = __builtin_amdgcn_exp2f(st[r]); rsum += p[r]; }
      unsigned int w0 = cvtpk(p[0], p[1]),  w1 = cvtpk(p[2], p[3]);
      unsigned int w2 = cvtpk(p[4], p[5]),  w3 = cvtpk(p[6], p[7]);
      unsigned int w4 = cvtpk(p[8], p[9]),  w5 = cvtpk(p[10], p[11]);
      unsigned int w6 = cvtpk(p[12], p[13]), w7 = cvtpk(p[14], p[15]);
      pl32swap(w0, w2); pl32swap(w1, w3);        // -> keys 8h+0..7   (s=0)
      pl32swap(w4, w6); pl32swap(w5, w7);        // -> keys 8h+16..23 (s=1)
      union { unsigned int u[4]; v8s v; } pa0, pa1;
      pa0.u[0] = w0; pa0.u[1] = w1; pa0.u[2] = w2; pa0.u[3] = w3;
      pa1.u[0] = w4; pa1.u[1] = w5; pa1.u[2] = w6; pa1.u[3] = w7;
#pragma unroll
      for (int s = 0; s < 2; ++s) {
        v8s pa = s ? pa1.v : pa0.v;
        int cb = mt * 4 + s * 2 + h;             // key chunk-of-8 index
        int rv0 = ln31, rv1 = 32 + ln31;
        v8s vb0 = *(const v8s*)&Vs[rv0 * 64 + ((cb ^ (rv0 & 7))) * 8];
        v8s vb1 = *(const v8s*)&Vs[rv1 * 64 + ((cb ^ (rv1 & 7))) * 8];
        acc0 = mfma32(pa, vb0, acc0);
        acc1 = mfma32(pa, vb1, acc1);
      }
    }
  }

  // row sums: lane l and l^32 hold complementary key-subsets for q=ln31
  float rtot = rsum + __shfl_xor(rsum, 32, 64);
  float inv = 1.0f / rtot;

  int qbase = qb * 128 + wq;
#pragma unroll
  for (int r = 0; r < 16; ++r) {
    int qr = (r & 3) + 8 * (r >> 2) + 4 * h;
    float ivr = __shfl(inv, qr, 64);             // inv lives in lane q
    size_t o = (size_t)(b * 2048 + qbase + qr) * 1024 + hH * 64 + ln31;
    out[o] = acc0[r] * ivr;
    out[o + 32] = acc1[r] * ivr;
  }
}

extern "C" void kernel_launch(void* const* d_in, const int* in_sizes, int n_in,
                              void* d_out, int out_size, void* d_ws, size_t ws_size,
                              hipStream_t stream) {
  const float* x = (const float*)d_in[0];   // [2,2048,1024]
  const float* w = (const float*)d_in[1];   // [1024,3072]
  float* out = (float*)d_out;

  char* ws = (char*)d_ws;
  unsigned short* xb = (unsigned short*)ws;                  // [4096][1024] bf16, 8 MB
  unsigned short* wT = (unsigned short*)(ws + 8388608);      // [3072][1024] bf16, 6 MB
  unsigned short* Cq = (unsigned short*)(ws + 14680064);     // [4096][2048] bf16 (Q|K)
  unsigned short* VT = (unsigned short*)(ws + 31457280);     // [32][64][2048] bf16

  cvt_x_kernel<<<4096, 256, 0, stream>>>((const float4*)x, (ushort4*)xb, 1048576);
  cvt_wT_kernel<<<dim3(96, 32), 256, 0, stream>>>(w, wT);
  qkv_gemm<<<dim3(64, 24), 256, 0, stream>>>(xb, wT, Cq, VT);
  attn_kernel<<<dim3(16, 32), 256, 0, stream>>>(Cq, VT, out);
}